// Round 2
// baseline (1175.143 us; speedup 1.0000x reference)
//
#include <hip/hip_runtime.h>
#include <cmath>

// Problem constants
constexpr int B_ = 64, N_ = 50000, L_ = 8, E_ = 100000, U_ = 20000, G_ = 20000, R_ = 64, D_ = 16, C_ = 2;

// Batch-chunked layout: per chunk of BC batch rows,
//   h[node] is a row of F = 4*BC float4s, f = b*4 + dc  (b in [0,BC), dc in [0,4))
//   logical h[c*BC + b][node][d] with d = dc*4 + j

__device__ __forceinline__ float4 add4(float4 a, float4 b) {
  return make_float4(a.x + b.x, a.y + b.y, a.z + b.z, a.w + b.w);
}
__device__ __forceinline__ float4 tanh4(float4 a) {
  return make_float4(tanhf(a.x), tanhf(a.y), tanhf(a.z), tanhf(a.w));
}

// ---------------- CSR build (layer-batched, batch-independent) ----------------

__global__ __launch_bounds__(256) void hist_kernel(
    const int* __restrict__ dst_pos, int* __restrict__ cnt) {
  int e = blockIdx.x * 256 + threadIdx.x;
  int li = blockIdx.y;
  if (e >= E_) return;
  atomicAdd(&cnt[li * U_ + dst_pos[li * E_ + e]], 1);
}

__global__ __launch_bounds__(1024) void scan_kernel(
    int* __restrict__ cnt_offs, int* __restrict__ cursor) {
  __shared__ int sd[1024];
  int li = blockIdx.x;
  int tid = threadIdx.x;
  int carry = 0;
  for (int base = 0; base < U_; base += 1024) {
    int i = base + tid;
    int v = (i < U_) ? cnt_offs[li * U_ + i] : 0;
    sd[tid] = v;
    __syncthreads();
    for (int off = 1; off < 1024; off <<= 1) {
      int t = (tid >= off) ? sd[tid - off] : 0;
      __syncthreads();
      sd[tid] += t;
      __syncthreads();
    }
    int excl = sd[tid] - v;
    if (i < U_) {
      cnt_offs[li * U_ + i] = carry + excl;
      cursor[li * U_ + i] = carry + excl;
    }
    int total = sd[1023];
    __syncthreads();
    carry += total;
  }
}

__global__ __launch_bounds__(256) void scatter_kernel(
    const int* __restrict__ dst_pos, const int* __restrict__ src,
    int* __restrict__ cursor, int* __restrict__ sorted_src) {
  int e = blockIdx.x * 256 + threadIdx.x;
  int li = blockIdx.y;
  if (e >= E_) return;
  int u = dst_pos[li * E_ + e];
  int p = atomicAdd(&cursor[li * U_ + u], 1);
  sorted_src[li * E_ + p] = src[li * E_ + e];
}

// ---------------- Per-chunk compute kernels ----------------

template <int BC>
__global__ __launch_bounds__(256) void gene_init_k(
    const float* __restrict__ X, const float* __restrict__ w_in,
    const float* __restrict__ b_in, const int* __restrict__ gene_map,
    float4* __restrict__ h4, int c) {
  constexpr int F = 4 * BC;
  int t = blockIdx.x * 256 + threadIdx.x;
  if (t >= G_ * BC) return;
  int g = t % G_;
  int b = t / G_;
  float x = X[(c * BC + b) * G_ + g];
  int node = gene_map[g];
  const float4* w4 = (const float4*)w_in;
  const float4* b4 = (const float4*)b_in;
#pragma unroll
  for (int dc = 0; dc < 4; ++dc) {
    float4 w = w4[dc], bb = b4[dc];
    float4 r = make_float4(fmaf(x, w.x, bb.x), fmaf(x, w.y, bb.y),
                           fmaf(x, w.z, bb.z), fmaf(x, w.w, bb.w));
    h4[(size_t)node * F + b * 4 + dc] = r;
  }
}

// Gather-sum + (sum)@W + bias + tanh -> agg
template <int BC>
__global__ __launch_bounds__(256) void agg_k(
    const float4* __restrict__ h4, const int* __restrict__ offs,
    const int* __restrict__ endo, const int* __restrict__ ssrc,
    const float* __restrict__ W, const float* __restrict__ bias,
    const int* __restrict__ dst_unique, float4* __restrict__ agg4, int li) {
  constexpr int F = 4 * BC;                  // float4 per node row
  constexpr int LPU = (F < 64) ? F : 64;     // lanes per u
  constexpr int UPW = 64 / LPU;              // u's per wave
  constexpr int RPL = (F + 63) / 64;         // float4 per lane
  __shared__ float4 Wlds[64];                // W[d][d'] as Wlds[d*4+dc]
  __shared__ float4 Alds[4 * UPW * F];
  int tid = threadIdx.x;
  ((float*)Wlds)[tid] = W[li * 256 + tid];
  int wave = tid >> 6, lane = tid & 63;
  int u_in_wave = lane / LPU;
  int li_u = lane % LPU;
  int ub = wave * UPW + u_in_wave;
  int u = blockIdx.x * (4 * UPW) + ub;
  float4 acc[RPL];
#pragma unroll
  for (int r = 0; r < RPL; ++r) acc[r] = make_float4(0, 0, 0, 0);
  int node = 0;
  if (u < U_) {
    int start = offs[li * U_ + u], end = endo[li * U_ + u];
    for (int e = start; e < end; ++e) {
      int s = ssrc[li * E_ + e];
      const float4* row = h4 + (size_t)s * F;
#pragma unroll
      for (int r = 0; r < RPL; ++r) acc[r] = add4(acc[r], row[li_u + r * 64]);
    }
#pragma unroll
    for (int r = 0; r < RPL; ++r) Alds[ub * F + li_u + r * 64] = acc[r];
    node = dst_unique[li * U_ + u];
  }
  __syncthreads();
  if (u < U_) {
    const float4* brow = (const float4*)bias + (size_t)node * 4;
#pragma unroll
    for (int r = 0; r < RPL; ++r) {
      int f = li_u + r * 64;
      int b = f >> 2, dc = f & 3;
      const float4* arow = &Alds[ub * F + b * 4];
      float4 m = make_float4(0, 0, 0, 0);
#pragma unroll
      for (int q = 0; q < 4; ++q) {
        float4 a4 = arow[q];
        float av[4] = {a4.x, a4.y, a4.z, a4.w};
#pragma unroll
        for (int j = 0; j < 4; ++j) {
          float s = av[j];
          float4 w = Wlds[(q * 4 + j) * 4 + dc];
          m.x = fmaf(s, w.x, m.x); m.y = fmaf(s, w.y, m.y);
          m.z = fmaf(s, w.z, m.z); m.w = fmaf(s, w.w, m.w);
        }
      }
      m = tanh4(add4(m, brow[dc]));
      agg4[(size_t)u * F + f] = m;
    }
  }
}

template <int BC>
__global__ __launch_bounds__(256) void update_k(
    float4* __restrict__ h4, const float4* __restrict__ agg4,
    const int* __restrict__ dst_unique, int li) {
  constexpr int F = 4 * BC;
  int t = blockIdx.x * 256 + threadIdx.x;
  if (t >= U_ * F) return;
  int u = t / F, f = t % F;  // F is a power of two
  int node = dst_unique[li * U_ + u];
  h4[(size_t)node * F + f] = agg4[t];
}

template <int BC>
__global__ __launch_bounds__(64) void head_k(
    const float4* __restrict__ h4, const float* __restrict__ W_head,
    const float* __restrict__ b_head, const int* __restrict__ root_ids,
    float* __restrict__ out, int c) {
  constexpr int F = 4 * BC;
  int bl = blockIdx.x;   // batch row within chunk
  int r = threadIdx.x;   // root index, R_ == 64 lanes
  int node = root_ids[r];
  const float4* row = h4 + (size_t)node * F + bl * 4;
  float acc0 = 0.f, acc1 = 0.f;
#pragma unroll
  for (int dc = 0; dc < 4; ++dc) {
    float4 v = row[dc];
    float vv[4] = {v.x, v.y, v.z, v.w};
#pragma unroll
    for (int j = 0; j < 4; ++j) {
      int d = dc * 4 + j;
      acc0 = fmaf(vv[j], W_head[r * 16 + d], acc0);
      acc1 = fmaf(vv[j], W_head[1024 + r * 16 + d], acc1);
    }
  }
  for (int off = 32; off; off >>= 1) {
    acc0 += __shfl_down(acc0, off, 64);
    acc1 += __shfl_down(acc1, off, 64);
  }
  if (r == 0) {
    out[(c * BC + bl) * 2 + 0] = acc0 + b_head[0];
    out[(c * BC + bl) * 2 + 1] = acc1 + b_head[1];
  }
}

__global__ void zero_out_k(float* out, int n) {
  int t = blockIdx.x * 256 + threadIdx.x;
  if (t < n) out[t] = 0.f;
}

// ---------------- Host side ----------------

template <int BC>
static void run_all(void* const* d_in, void* d_out, void* d_ws, hipStream_t stream) {
  const float* X = (const float*)d_in[0];
  const float* w_in = (const float*)d_in[1];
  const float* b_in = (const float*)d_in[2];
  const float* W = (const float*)d_in[3];
  const float* bias = (const float*)d_in[4];
  const float* W_head = (const float*)d_in[5];
  const float* b_head = (const float*)d_in[6];
  const int* gene_map = (const int*)d_in[7];
  const int* src = (const int*)d_in[8];
  const int* dst_pos = (const int*)d_in[9];
  const int* dst_unique = (const int*)d_in[10];
  const int* root_ids = (const int*)d_in[11];
  float* out = (float*)d_out;

  constexpr int F = 4 * BC;
  const size_t h_bytes = (size_t)N_ * F * 16;       // N * BC * 64
  const size_t agg_bytes = (size_t)U_ * F * 16;
  const size_t cnt_bytes = (size_t)L_ * U_ * 4;

  char* ws = (char*)d_ws;
  float4* h4 = (float4*)ws;
  float4* agg4 = (float4*)(ws + h_bytes);
  int* offs = (int*)(ws + h_bytes + agg_bytes);
  int* cursor = (int*)(ws + h_bytes + agg_bytes + cnt_bytes);
  int* ssrc = (int*)(ws + h_bytes + agg_bytes + 2 * cnt_bytes);

  // CSR build for all layers, once
  hipMemsetAsync(offs, 0, cnt_bytes, stream);
  dim3 egrid((E_ + 255) / 256, L_);
  hist_kernel<<<egrid, 256, 0, stream>>>(dst_pos, offs);
  scan_kernel<<<L_, 1024, 0, stream>>>(offs, cursor);
  scatter_kernel<<<egrid, 256, 0, stream>>>(dst_pos, src, cursor, ssrc);

  constexpr int nchunks = B_ / BC;
  constexpr int UPW = (F < 64) ? (64 / F) : 1;
  const int agg_grid = (U_ + 4 * UPW - 1) / (4 * UPW);
  const int upd_grid = (U_ * F + 255) / 256;
  const int gi_grid = (G_ * BC + 255) / 256;

  for (int c = 0; c < nchunks; ++c) {
    hipMemsetAsync(h4, 0, h_bytes, stream);
    gene_init_k<BC><<<gi_grid, 256, 0, stream>>>(X, w_in, b_in, gene_map, h4, c);
    for (int li = 0; li < L_; ++li) {
      agg_k<BC><<<agg_grid, 256, 0, stream>>>(h4, offs, cursor, ssrc, W, bias,
                                              dst_unique, agg4, li);
      update_k<BC><<<upd_grid, 256, 0, stream>>>(h4, agg4, dst_unique, li);
    }
    head_k<BC><<<BC, 64, 0, stream>>>(h4, W_head, b_head, root_ids, out, c);
  }
}

static size_t need_bytes(int BC) {
  return (size_t)N_ * BC * 64 + (size_t)U_ * BC * 64 +
         2 * (size_t)L_ * U_ * 4 + (size_t)L_ * E_ * 4;
}

extern "C" void kernel_launch(void* const* d_in, const int* in_sizes, int n_in,
                              void* d_out, int out_size, void* d_ws, size_t ws_size,
                              hipStream_t stream) {
  if (ws_size >= need_bytes(32)) {
    run_all<32>(d_in, d_out, d_ws, stream);
  } else if (ws_size >= need_bytes(16)) {
    run_all<16>(d_in, d_out, d_ws, stream);
  } else if (ws_size >= need_bytes(8)) {
    run_all<8>(d_in, d_out, d_ws, stream);
  } else if (ws_size >= need_bytes(4)) {
    run_all<4>(d_in, d_out, d_ws, stream);
  } else if (ws_size >= need_bytes(1)) {
    run_all<1>(d_in, d_out, d_ws, stream);
  } else {
    zero_out_k<<<(out_size + 255) / 256, 256, 0, stream>>>((float*)d_out, out_size);
  }
}

// Round 3
// 853.167 us; speedup vs baseline: 1.3774x; 1.3774x over previous
//
#include <hip/hip_runtime.h>
#include <hip/hip_fp16.h>
#include <cmath>

// Problem constants
constexpr int B_ = 64, N_ = 50000, L_ = 8, E_ = 100000, U_ = 20000, G_ = 20000, R_ = 64, D_ = 16, C_ = 2;

// h stored fp16: h[node][b][d], d-contiguous, 16 halfs per (node,b) = 32 B.
// Row = BC*32 bytes = F float4s, F = BC*2. float4 chunk f = b*2 + dh
// (dh in {0,1}, covering d = dh*8 .. dh*8+7).

// ---------------- CSR build (batch-independent) ----------------

__global__ __launch_bounds__(256) void hist_kernel(
    const int* __restrict__ dst_pos, int* __restrict__ cnt) {
  int e = blockIdx.x * 256 + threadIdx.x;
  int li = blockIdx.y;
  if (e >= E_) return;
  atomicAdd(&cnt[li * U_ + dst_pos[li * E_ + e]], 1);
}

__global__ __launch_bounds__(1024) void scan_kernel(
    int* __restrict__ cnt_offs, int* __restrict__ cursor) {
  __shared__ int sd[1024];
  int li = blockIdx.x;
  int tid = threadIdx.x;
  int carry = 0;
  for (int base = 0; base < U_; base += 1024) {
    int i = base + tid;
    int v = (i < U_) ? cnt_offs[li * U_ + i] : 0;
    sd[tid] = v;
    __syncthreads();
    for (int off = 1; off < 1024; off <<= 1) {
      int t = (tid >= off) ? sd[tid - off] : 0;
      __syncthreads();
      sd[tid] += t;
      __syncthreads();
    }
    int excl = sd[tid] - v;
    if (i < U_) {
      cnt_offs[li * U_ + i] = carry + excl;
      cursor[li * U_ + i] = carry + excl;
    }
    int total = sd[1023];
    __syncthreads();
    carry += total;
  }
}

__global__ __launch_bounds__(256) void scatter_kernel(
    const int* __restrict__ dst_pos, const int* __restrict__ src,
    int* __restrict__ cursor, int* __restrict__ sorted_src) {
  int e = blockIdx.x * 256 + threadIdx.x;
  int li = blockIdx.y;
  if (e >= E_) return;
  int u = dst_pos[li * E_ + e];
  int p = atomicAdd(&cursor[li * U_ + u], 1);
  sorted_src[li * E_ + p] = src[li * E_ + e];
}

// ---------------- Per-chunk compute ----------------

template <int BC>
__global__ __launch_bounds__(256) void gene_init_k(
    const float* __restrict__ X, const float* __restrict__ w_in,
    const float* __restrict__ b_in, const int* __restrict__ gene_map,
    float4* __restrict__ h4, int c) {
  constexpr int F = BC * 2;
  int t = blockIdx.x * 256 + threadIdx.x;
  if (t >= G_ * BC) return;
  int b = t % BC;
  int g = t / BC;
  float x = X[(c * BC + b) * G_ + g];
  int node = gene_map[g];
  float4 out[2];
  __half2* oh = reinterpret_cast<__half2*>(out);
#pragma unroll
  for (int k = 0; k < 8; ++k) {
    float r0 = fmaf(x, w_in[2 * k], b_in[2 * k]);
    float r1 = fmaf(x, w_in[2 * k + 1], b_in[2 * k + 1]);
    oh[k] = __float22half2_rn(make_float2(r0, r1));
  }
  h4[(size_t)node * F + b * 2] = out[0];
  h4[(size_t)node * F + b * 2 + 1] = out[1];
}

// One u per LPU lanes: gather-sum (fp32 acc) + @W + bias + tanh -> agg (fp16)
template <int BC>
__global__ __launch_bounds__(256) void agg_k(
    const float4* __restrict__ h4, const int* __restrict__ offs,
    const int* __restrict__ endo, const int* __restrict__ ssrc,
    const float* __restrict__ W, const float* __restrict__ bias,
    const int* __restrict__ dst_unique, float4* __restrict__ agg4, int li) {
  constexpr int F = BC * 2;                 // float4 chunks per node row
  constexpr int LPU = (F < 64) ? F : 64;    // lanes per u
  constexpr int UPW = 64 / LPU;             // u's per wave
  constexpr int RPL = (F + 63) / 64;        // chunks per lane
  __shared__ float Wlds[256];               // W[d][d']
  __shared__ float Alds[4 * UPW][16][BC];   // [u_in_block][d][b]
  int tid = threadIdx.x;
  Wlds[tid] = W[li * 256 + tid];
  int wave = tid >> 6, lane = tid & 63;
  int u_in_wave = lane / LPU;
  int li_u = lane % LPU;
  int ub = wave * UPW + u_in_wave;
  int u = blockIdx.x * (4 * UPW) + ub;      // U_ % (4*UPW) == 0 -> always < U_

  int start = offs[li * U_ + u];
  int end = endo[li * U_ + u];

  float acc[RPL][8], acc2[RPL][8];
#pragma unroll
  for (int r = 0; r < RPL; ++r)
#pragma unroll
    for (int j = 0; j < 8; ++j) { acc[r][j] = 0.f; acc2[r][j] = 0.f; }

  int e = start;
  for (; e + 1 < end; e += 2) {
    int s0 = ssrc[li * E_ + e];
    int s1 = ssrc[li * E_ + e + 1];
    float4 v0[RPL], v1[RPL];
#pragma unroll
    for (int r = 0; r < RPL; ++r) {
      v0[r] = h4[(size_t)s0 * F + li_u + r * 64];
      v1[r] = h4[(size_t)s1 * F + li_u + r * 64];
    }
#pragma unroll
    for (int r = 0; r < RPL; ++r) {
      const __half2* p0 = reinterpret_cast<const __half2*>(&v0[r]);
      const __half2* p1 = reinterpret_cast<const __half2*>(&v1[r]);
#pragma unroll
      for (int k = 0; k < 4; ++k) {
        float2 f0 = __half22float2(p0[k]);
        float2 f1 = __half22float2(p1[k]);
        acc[r][2 * k] += f0.x;  acc[r][2 * k + 1] += f0.y;
        acc2[r][2 * k] += f1.x; acc2[r][2 * k + 1] += f1.y;
      }
    }
  }
  if (e < end) {
    int s0 = ssrc[li * E_ + e];
#pragma unroll
    for (int r = 0; r < RPL; ++r) {
      float4 v = h4[(size_t)s0 * F + li_u + r * 64];
      const __half2* p = reinterpret_cast<const __half2*>(&v);
#pragma unroll
      for (int k = 0; k < 4; ++k) {
        float2 f = __half22float2(p[k]);
        acc[r][2 * k] += f.x; acc[r][2 * k + 1] += f.y;
      }
    }
  }
  // merge + stage sums into LDS [d][b]
#pragma unroll
  for (int r = 0; r < RPL; ++r) {
    int f = li_u + r * 64;
    int b = f >> 1, dh = f & 1;
#pragma unroll
    for (int j = 0; j < 8; ++j)
      Alds[ub][dh * 8 + j][b] = acc[r][j] + acc2[r][j];
  }
  __syncthreads();

  int node = dst_unique[li * U_ + u];
#pragma unroll
  for (int r = 0; r < RPL; ++r) {
    int f = li_u + r * 64;
    int b = f >> 1, dh = f & 1;
    float a[16];
#pragma unroll
    for (int d = 0; d < 16; ++d) a[d] = Alds[ub][d][b];
    float m[8];
#pragma unroll
    for (int j = 0; j < 8; ++j) m[j] = 0.f;
#pragma unroll
    for (int d = 0; d < 16; ++d) {
      float s = a[d];
#pragma unroll
      for (int j = 0; j < 8; ++j)
        m[j] = fmaf(s, Wlds[d * 16 + dh * 8 + j], m[j]);
    }
    const float* bptr = bias + (size_t)node * 16 + dh * 8;
    float4 outv;
    __half2* oh = reinterpret_cast<__half2*>(&outv);
#pragma unroll
    for (int k = 0; k < 4; ++k) {
      float t0 = tanhf(m[2 * k] + bptr[2 * k]);
      float t1 = tanhf(m[2 * k + 1] + bptr[2 * k + 1]);
      oh[k] = __float22half2_rn(make_float2(t0, t1));
    }
    agg4[(size_t)u * F + f] = outv;
  }
}

template <int BC>
__global__ __launch_bounds__(256) void update_k(
    float4* __restrict__ h4, const float4* __restrict__ agg4,
    const int* __restrict__ dst_unique, int li) {
  constexpr int F = BC * 2;
  int t = blockIdx.x * 256 + threadIdx.x;
  if (t >= U_ * F) return;
  int u = t / F, f = t % F;  // F is a power of two
  int node = dst_unique[li * U_ + u];
  h4[(size_t)node * F + f] = agg4[t];
}

template <int BC>
__global__ __launch_bounds__(64) void head_k(
    const float4* __restrict__ h4, const float* __restrict__ W_head,
    const float* __restrict__ b_head, const int* __restrict__ root_ids,
    float* __restrict__ out, int c) {
  constexpr int F = BC * 2;
  int bl = blockIdx.x;   // batch row within chunk
  int r = threadIdx.x;   // root index (64 lanes)
  int node = root_ids[r];
  float4 p0 = h4[(size_t)node * F + bl * 2];
  float4 p1 = h4[(size_t)node * F + bl * 2 + 1];
  float v[16];
  const __half2* ph0 = reinterpret_cast<const __half2*>(&p0);
  const __half2* ph1 = reinterpret_cast<const __half2*>(&p1);
#pragma unroll
  for (int k = 0; k < 4; ++k) {
    float2 f0 = __half22float2(ph0[k]);
    float2 f1 = __half22float2(ph1[k]);
    v[2 * k] = f0.x; v[2 * k + 1] = f0.y;
    v[8 + 2 * k] = f1.x; v[8 + 2 * k + 1] = f1.y;
  }
  float acc0 = 0.f, acc1 = 0.f;
#pragma unroll
  for (int d = 0; d < 16; ++d) {
    acc0 = fmaf(v[d], W_head[r * 16 + d], acc0);
    acc1 = fmaf(v[d], W_head[1024 + r * 16 + d], acc1);
  }
  for (int off = 32; off; off >>= 1) {
    acc0 += __shfl_down(acc0, off, 64);
    acc1 += __shfl_down(acc1, off, 64);
  }
  if (r == 0) {
    out[(c * BC + bl) * 2 + 0] = acc0 + b_head[0];
    out[(c * BC + bl) * 2 + 1] = acc1 + b_head[1];
  }
}

__global__ void zero_out_k(float* out, int n) {
  int t = blockIdx.x * 256 + threadIdx.x;
  if (t < n) out[t] = 0.f;
}

// ---------------- Host side ----------------

template <int BC>
static void run_all(void* const* d_in, void* d_out, void* d_ws, hipStream_t stream) {
  const float* X = (const float*)d_in[0];
  const float* w_in = (const float*)d_in[1];
  const float* b_in = (const float*)d_in[2];
  const float* W = (const float*)d_in[3];
  const float* bias = (const float*)d_in[4];
  const float* W_head = (const float*)d_in[5];
  const float* b_head = (const float*)d_in[6];
  const int* gene_map = (const int*)d_in[7];
  const int* src = (const int*)d_in[8];
  const int* dst_pos = (const int*)d_in[9];
  const int* dst_unique = (const int*)d_in[10];
  const int* root_ids = (const int*)d_in[11];
  float* out = (float*)d_out;

  constexpr int F = BC * 2;
  const size_t h_bytes = (size_t)N_ * F * 16;
  const size_t agg_bytes = (size_t)U_ * F * 16;
  const size_t cnt_bytes = (size_t)L_ * U_ * 4;

  char* ws = (char*)d_ws;
  float4* h4 = (float4*)ws;
  float4* agg4 = (float4*)(ws + h_bytes);
  int* offs = (int*)(ws + h_bytes + agg_bytes);
  int* cursor = (int*)(ws + h_bytes + agg_bytes + cnt_bytes);
  int* ssrc = (int*)(ws + h_bytes + agg_bytes + 2 * cnt_bytes);

  hipMemsetAsync(offs, 0, cnt_bytes, stream);
  dim3 egrid((E_ + 255) / 256, L_);
  hist_kernel<<<egrid, 256, 0, stream>>>(dst_pos, offs);
  scan_kernel<<<L_, 1024, 0, stream>>>(offs, cursor);
  scatter_kernel<<<egrid, 256, 0, stream>>>(dst_pos, src, cursor, ssrc);

  constexpr int nchunks = B_ / BC;
  constexpr int LPU = (F < 64) ? F : 64;
  constexpr int UPW = 64 / LPU;
  const int agg_grid = U_ / (4 * UPW);
  const int upd_grid = (U_ * F + 255) / 256;
  const int gi_grid = (G_ * BC + 255) / 256;

  for (int c = 0; c < nchunks; ++c) {
    hipMemsetAsync(h4, 0, h_bytes, stream);
    gene_init_k<BC><<<gi_grid, 256, 0, stream>>>(X, w_in, b_in, gene_map, h4, c);
    for (int li = 0; li < L_; ++li) {
      agg_k<BC><<<agg_grid, 256, 0, stream>>>(h4, offs, cursor, ssrc, W, bias,
                                              dst_unique, agg4, li);
      update_k<BC><<<upd_grid, 256, 0, stream>>>(h4, agg4, dst_unique, li);
    }
    head_k<BC><<<BC, 64, 0, stream>>>(h4, W_head, b_head, root_ids, out, c);
  }
}

static size_t need_bytes(int BC) {
  return (size_t)N_ * BC * 32 + (size_t)U_ * BC * 32 +
         2 * (size_t)L_ * U_ * 4 + (size_t)L_ * E_ * 4;
}

extern "C" void kernel_launch(void* const* d_in, const int* in_sizes, int n_in,
                              void* d_out, int out_size, void* d_ws, size_t ws_size,
                              hipStream_t stream) {
  if (ws_size >= need_bytes(64)) {
    run_all<64>(d_in, d_out, d_ws, stream);
  } else if (ws_size >= need_bytes(32)) {
    run_all<32>(d_in, d_out, d_ws, stream);
  } else if (ws_size >= need_bytes(16)) {
    run_all<16>(d_in, d_out, d_ws, stream);
  } else {
    zero_out_k<<<(out_size + 255) / 256, 256, 0, stream>>>((float*)d_out, out_size);
  }
}

// Round 4
// 809.134 us; speedup vs baseline: 1.4523x; 1.0544x over previous
//
#include <hip/hip_runtime.h>
#include <hip/hip_fp16.h>
#include <cmath>

// Problem constants
constexpr int B_ = 64, N_ = 50000, L_ = 8, E_ = 100000, U_ = 20000, G_ = 20000, R_ = 64, D_ = 16, C_ = 2;
constexpr int EPL_ = E_ + 3 * U_;  // padded edges per layer (max)

// h stored fp16: h[node][b][d], d-contiguous, 16 halfs per (node,b) = 32 B.
// Row = BC*32 bytes = F float4s, F = BC*2. float4 chunk f = b*2 + dh.
// Node N_ is a reserved all-zero row (padding target).

// ---------------- CSR build (batch-independent, padded to multiples of 4) ----

__global__ __launch_bounds__(256) void hist_kernel(
    const int* __restrict__ dst_pos, int* __restrict__ cnt) {
  int e = blockIdx.x * 256 + threadIdx.x;
  int li = blockIdx.y;
  if (e >= E_) return;
  atomicAdd(&cnt[li * U_ + dst_pos[li * E_ + e]], 1);
}

// offs[li*(U+1)+u] = padded exclusive scan; offs[li*(U+1)+U] = padded total.
// cursor = real start (same as padded start).
__global__ __launch_bounds__(1024) void scan_kernel(
    const int* __restrict__ cnt, int* __restrict__ offs, int* __restrict__ cursor) {
  __shared__ int sd[1024];
  int li = blockIdx.x;
  int tid = threadIdx.x;
  int carry = 0;
  for (int base = 0; base < U_; base += 1024) {
    int i = base + tid;
    int c = (i < U_) ? cnt[li * U_ + i] : 0;
    int v = (c + 3) & ~3;
    sd[tid] = v;
    __syncthreads();
    for (int off = 1; off < 1024; off <<= 1) {
      int t = (tid >= off) ? sd[tid - off] : 0;
      __syncthreads();
      sd[tid] += t;
      __syncthreads();
    }
    int excl = sd[tid] - v;
    if (i < U_) {
      offs[li * (U_ + 1) + i] = carry + excl;
      cursor[li * U_ + i] = carry + excl;
    }
    int total = sd[1023];
    __syncthreads();
    carry += total;
  }
  if (tid == 0) offs[li * (U_ + 1) + U_] = carry;
}

__global__ __launch_bounds__(256) void scatter_kernel(
    const int* __restrict__ dst_pos, const int* __restrict__ src,
    int* __restrict__ cursor, int* __restrict__ ssrc) {
  int e = blockIdx.x * 256 + threadIdx.x;
  int li = blockIdx.y;
  if (e >= E_) return;
  int u = dst_pos[li * E_ + e];
  int p = atomicAdd(&cursor[li * U_ + u], 1);
  ssrc[(size_t)li * EPL_ + p] = src[li * E_ + e];
}

// Fill padding slots [real_end, padded_end) with the zero-row index N_.
__global__ __launch_bounds__(256) void pad_fill_k(
    const int* __restrict__ cursor, const int* __restrict__ offs,
    int* __restrict__ ssrc) {
  int t = blockIdx.x * 256 + threadIdx.x;
  if (t >= L_ * U_) return;
  int li = t / U_, u = t % U_;
  int end = cursor[li * U_ + u];
  int pend = offs[li * (U_ + 1) + u + 1];
  int* sp = ssrc + (size_t)li * EPL_;
  for (int p = end; p < pend; ++p) sp[p] = N_;
}

// ---------------- Per-chunk compute ----------------

template <int BC>
__global__ __launch_bounds__(256) void gene_init_k(
    const float* __restrict__ X, const float* __restrict__ w_in,
    const float* __restrict__ b_in, const int* __restrict__ gene_map,
    float4* __restrict__ h4, int c) {
  constexpr int F = BC * 2;
  int t = blockIdx.x * 256 + threadIdx.x;
  if (t >= G_ * BC) return;
  int b = t % BC;
  int g = t / BC;
  float x = X[(c * BC + b) * G_ + g];
  int node = gene_map[g];
  float4 out[2];
  __half2* oh = reinterpret_cast<__half2*>(out);
#pragma unroll
  for (int k = 0; k < 8; ++k) {
    float r0 = fmaf(x, w_in[2 * k], b_in[2 * k]);
    float r1 = fmaf(x, w_in[2 * k + 1], b_in[2 * k + 1]);
    oh[k] = __float22half2_rn(make_float2(r0, r1));
  }
  h4[(size_t)node * F + b * 2] = out[0];
  h4[(size_t)node * F + b * 2 + 1] = out[1];
}

// Gather-sum (packed fp16 acc, unroll-4, index prefetch) + @W + bias + tanh.
template <int BC>
__global__ __launch_bounds__(256) void agg_k(
    const float4* __restrict__ h4, const int* __restrict__ offs,
    const int* __restrict__ ssrc, const float* __restrict__ W,
    const float* __restrict__ bias, const int* __restrict__ dst_unique,
    float4* __restrict__ agg4, int li) {
  constexpr int F = BC * 2;                 // float4 chunks per node row
  constexpr int LPU = (F < 64) ? F : 64;    // lanes per u
  constexpr int UPW = 64 / LPU;             // u's per wave
  constexpr int RPL = (F + 63) / 64;        // chunks per lane
  __shared__ float Wlds[256];               // W[d][d']
  __shared__ float Alds[4 * UPW][16][BC];   // [u_in_block][d][b]
  int tid = threadIdx.x;
  Wlds[tid] = W[li * 256 + tid];
  int wave = tid >> 6, lane = tid & 63;
  int ub = wave * UPW + lane / LPU;
  int li_u = lane % LPU;
  int u = blockIdx.x * (4 * UPW) + ub;      // U_ % (4*UPW) == 0

  int start = offs[li * (U_ + 1) + u];
  int pend = offs[li * (U_ + 1) + u + 1];   // padded: (pend-start)%4==0
  int tot = offs[li * (U_ + 1) + U_];
  const int* sp = ssrc + (size_t)li * EPL_;

  __half2 acc[4][RPL][4];
#pragma unroll
  for (int j = 0; j < 4; ++j)
#pragma unroll
    for (int r = 0; r < RPL; ++r)
#pragma unroll
      for (int k = 0; k < 4; ++k) acc[j][r][k] = __half2half2(__float2half(0.f));

  int idx[4];
#pragma unroll
  for (int j = 0; j < 4; ++j) idx[j] = sp[min(start + j, tot - 1)];

  for (int e = start; e < pend; e += 4) {
    float4 v[4][RPL];
#pragma unroll
    for (int j = 0; j < 4; ++j)
#pragma unroll
      for (int r = 0; r < RPL; ++r)
        v[j][r] = h4[(size_t)idx[j] * F + li_u + r * 64];
    int nb = e + 4;
#pragma unroll
    for (int j = 0; j < 4; ++j) idx[j] = sp[min(nb + j, tot - 1)];
#pragma unroll
    for (int j = 0; j < 4; ++j)
#pragma unroll
      for (int r = 0; r < RPL; ++r) {
        const __half2* p = reinterpret_cast<const __half2*>(&v[j][r]);
#pragma unroll
        for (int k = 0; k < 4; ++k) acc[j][r][k] = __hadd2(acc[j][r][k], p[k]);
      }
  }

  // merge 4 accumulators in fp32, stage into LDS [d][b]
#pragma unroll
  for (int r = 0; r < RPL; ++r) {
    int f = li_u + r * 64;
    int b = f >> 1, dh = f & 1;
#pragma unroll
    for (int k = 0; k < 4; ++k) {
      float2 f0 = __half22float2(acc[0][r][k]);
      float2 f1 = __half22float2(acc[1][r][k]);
      float2 f2 = __half22float2(acc[2][r][k]);
      float2 f3 = __half22float2(acc[3][r][k]);
      Alds[ub][dh * 8 + 2 * k][b] = (f0.x + f1.x) + (f2.x + f3.x);
      Alds[ub][dh * 8 + 2 * k + 1][b] = (f0.y + f1.y) + (f2.y + f3.y);
    }
  }
  __syncthreads();

  int node = dst_unique[li * U_ + u];
#pragma unroll
  for (int r = 0; r < RPL; ++r) {
    int f = li_u + r * 64;
    int b = f >> 1, dh = f & 1;
    float a[16];
#pragma unroll
    for (int d = 0; d < 16; ++d) a[d] = Alds[ub][d][b];
    float m[8];
#pragma unroll
    for (int j = 0; j < 8; ++j) m[j] = 0.f;
#pragma unroll
    for (int d = 0; d < 16; ++d) {
      float s = a[d];
#pragma unroll
      for (int j = 0; j < 8; ++j)
        m[j] = fmaf(s, Wlds[d * 16 + dh * 8 + j], m[j]);
    }
    const float* bptr = bias + (size_t)node * 16 + dh * 8;
    float4 outv;
    __half2* oh = reinterpret_cast<__half2*>(&outv);
#pragma unroll
    for (int k = 0; k < 4; ++k) {
      float t0 = tanhf(m[2 * k] + bptr[2 * k]);
      float t1 = tanhf(m[2 * k + 1] + bptr[2 * k + 1]);
      oh[k] = __float22half2_rn(make_float2(t0, t1));
    }
    agg4[(size_t)u * F + f] = outv;
  }
}

template <int BC>
__global__ __launch_bounds__(256) void update_k(
    float4* __restrict__ h4, const float4* __restrict__ agg4,
    const int* __restrict__ dst_unique, int li) {
  constexpr int F = BC * 2;
  int t = blockIdx.x * 256 + threadIdx.x;
  if (t >= U_ * F) return;
  int u = t / F, f = t % F;
  int node = dst_unique[li * U_ + u];
  h4[(size_t)node * F + f] = agg4[t];
}

template <int BC>
__global__ __launch_bounds__(64) void head_k(
    const float4* __restrict__ h4, const float* __restrict__ W_head,
    const float* __restrict__ b_head, const int* __restrict__ root_ids,
    float* __restrict__ out, int c) {
  constexpr int F = BC * 2;
  int bl = blockIdx.x;
  int r = threadIdx.x;
  int node = root_ids[r];
  float4 p0 = h4[(size_t)node * F + bl * 2];
  float4 p1 = h4[(size_t)node * F + bl * 2 + 1];
  float v[16];
  const __half2* ph0 = reinterpret_cast<const __half2*>(&p0);
  const __half2* ph1 = reinterpret_cast<const __half2*>(&p1);
#pragma unroll
  for (int k = 0; k < 4; ++k) {
    float2 f0 = __half22float2(ph0[k]);
    float2 f1 = __half22float2(ph1[k]);
    v[2 * k] = f0.x; v[2 * k + 1] = f0.y;
    v[8 + 2 * k] = f1.x; v[8 + 2 * k + 1] = f1.y;
  }
  float acc0 = 0.f, acc1 = 0.f;
#pragma unroll
  for (int d = 0; d < 16; ++d) {
    acc0 = fmaf(v[d], W_head[r * 16 + d], acc0);
    acc1 = fmaf(v[d], W_head[1024 + r * 16 + d], acc1);
  }
  for (int off = 32; off; off >>= 1) {
    acc0 += __shfl_down(acc0, off, 64);
    acc1 += __shfl_down(acc1, off, 64);
  }
  if (r == 0) {
    out[(c * BC + bl) * 2 + 0] = acc0 + b_head[0];
    out[(c * BC + bl) * 2 + 1] = acc1 + b_head[1];
  }
}

__global__ void zero_out_k(float* out, int n) {
  int t = blockIdx.x * 256 + threadIdx.x;
  if (t < n) out[t] = 0.f;
}

// ---------------- Host side ----------------

template <int BC>
static void run_all(void* const* d_in, void* d_out, void* d_ws, hipStream_t stream) {
  const float* X = (const float*)d_in[0];
  const float* w_in = (const float*)d_in[1];
  const float* b_in = (const float*)d_in[2];
  const float* W = (const float*)d_in[3];
  const float* bias = (const float*)d_in[4];
  const float* W_head = (const float*)d_in[5];
  const float* b_head = (const float*)d_in[6];
  const int* gene_map = (const int*)d_in[7];
  const int* src = (const int*)d_in[8];
  const int* dst_pos = (const int*)d_in[9];
  const int* dst_unique = (const int*)d_in[10];
  const int* root_ids = (const int*)d_in[11];
  float* out = (float*)d_out;

  constexpr int F = BC * 2;
  const size_t h_bytes = (size_t)(N_ + 1) * F * 16;  // + zero row
  const size_t agg_bytes = (size_t)U_ * F * 16;
  const size_t cnt_bytes = (size_t)L_ * U_ * 4;
  const size_t offs_bytes = (size_t)L_ * (U_ + 1) * 4;
  const size_t cur_bytes = (size_t)L_ * U_ * 4;

  char* ws = (char*)d_ws;
  float4* h4 = (float4*)ws;
  float4* agg4 = (float4*)(ws + h_bytes);
  int* cnt = (int*)(ws + h_bytes + agg_bytes);
  int* offs = (int*)(ws + h_bytes + agg_bytes + cnt_bytes);
  int* cursor = (int*)(ws + h_bytes + agg_bytes + cnt_bytes + offs_bytes);
  int* ssrc = (int*)(ws + h_bytes + agg_bytes + cnt_bytes + offs_bytes + cur_bytes);

  hipMemsetAsync(cnt, 0, cnt_bytes, stream);
  dim3 egrid((E_ + 255) / 256, L_);
  hist_kernel<<<egrid, 256, 0, stream>>>(dst_pos, cnt);
  scan_kernel<<<L_, 1024, 0, stream>>>(cnt, offs, cursor);
  scatter_kernel<<<egrid, 256, 0, stream>>>(dst_pos, src, cursor, ssrc);
  pad_fill_k<<<(L_ * U_ + 255) / 256, 256, 0, stream>>>(cursor, offs, ssrc);

  constexpr int nchunks = B_ / BC;
  constexpr int LPU = (F < 64) ? F : 64;
  constexpr int UPW = 64 / LPU;
  const int agg_grid = U_ / (4 * UPW);
  const int upd_grid = (U_ * F + 255) / 256;
  const int gi_grid = (G_ * BC + 255) / 256;

  for (int c = 0; c < nchunks; ++c) {
    hipMemsetAsync(h4, 0, h_bytes, stream);
    gene_init_k<BC><<<gi_grid, 256, 0, stream>>>(X, w_in, b_in, gene_map, h4, c);
    for (int li = 0; li < L_; ++li) {
      agg_k<BC><<<agg_grid, 256, 0, stream>>>(h4, offs, ssrc, W, bias,
                                              dst_unique, agg4, li);
      update_k<BC><<<upd_grid, 256, 0, stream>>>(h4, agg4, dst_unique, li);
    }
    head_k<BC><<<BC, 64, 0, stream>>>(h4, W_head, b_head, root_ids, out, c);
  }
}

static size_t need_bytes(int BC) {
  return (size_t)(N_ + 1) * BC * 32 + (size_t)U_ * BC * 32 +
         (size_t)L_ * U_ * 4 * 2 + (size_t)L_ * (U_ + 1) * 4 +
         (size_t)L_ * EPL_ * 4;
}

extern "C" void kernel_launch(void* const* d_in, const int* in_sizes, int n_in,
                              void* d_out, int out_size, void* d_ws, size_t ws_size,
                              hipStream_t stream) {
  if (ws_size >= need_bytes(64)) {
    run_all<64>(d_in, d_out, d_ws, stream);
  } else if (ws_size >= need_bytes(32)) {
    run_all<32>(d_in, d_out, d_ws, stream);
  } else if (ws_size >= need_bytes(16)) {
    run_all<16>(d_in, d_out, d_ws, stream);
  } else {
    zero_out_k<<<(out_size + 255) / 256, 256, 0, stream>>>((float*)d_out, out_size);
  }
}